// Round 12
// baseline (481.161 us; speedup 1.0000x reference)
//
#include <hip/hip_runtime.h>
#include <hip/hip_bf16.h>

#define NB 8192
#define SROW 391

// ---- weight ws layout (floats) ----
#define TW      22848
#define W_WIH   0
#define W_WHH   1536
#define W_BSUM  17920
#define W_WTS   18176
#define W_BTS   22272
#define W_WOS   22336
#define W_BOS   22784
#define W_OUT   68544
#define WO_WIHO 0
#define WO_WHHO 32768
#define WO_BSUM 49152
#define WO_W1   49408
#define WO_B1   53504
#define WO_W2   53568
#define WO_B2   54144
#define WF_TOTAL 122697

typedef unsigned short u16;
typedef __attribute__((ext_vector_type(8))) short short8;
typedef __attribute__((ext_vector_type(4))) float float4v;

#define MFMA16(a, b, c) __builtin_amdgcn_mfma_f32_16x16x32_bf16((a), (b), (c), 0, 0, 0)

__device__ __forceinline__ float bf2f(u16 u){ return __uint_as_float(((unsigned)u) << 16); }
__device__ __forceinline__ u16 f2bf(float f){
  unsigned x = __float_as_uint(f);
  unsigned r = (x + 0x7FFFu + ((x >> 16) & 1u)) >> 16;   // RNE
  return (u16)r;
}
__device__ __forceinline__ bool isnanf32(float f){
  unsigned x = __float_as_uint(f);
  return (x & 0x7FFFFFFFu) > 0x7F800000u;
}
__device__ __forceinline__ float ldin(const void* p, size_t i, bool isbf){
  if (isbf) return bf2f(((const u16*)p)[i]);
  return ((const float*)p)[i];
}
__device__ __forceinline__ float sigm(float x){ return __fdividef(1.0f, 1.0f + __expf(-x)); }
__device__ __forceinline__ float tanh_f(float x){ return __fdividef(2.0f, 1.0f + __expf(-2.0f * x)) - 1.0f; }

__device__ __forceinline__ bool detect_bf(const void* whh0){
  const u16* u = (const u16*)whh0;
  const int l = threadIdx.x & 63;
  int e = (u[2 * l] >> 7) & 0xFF;
  unsigned long long m = __ballot(e >= 100 && e <= 141);
  return __popcll(m) >= 32;
}

struct Seg { int src; int src2; int soff; int dst; int n; };
struct SegTab { Seg s[35]; };
struct PtrTab { const void* p[36]; };

// ---------- kernel W: weights -> fp32; publish dtype flag; zero histogram ----------
__global__ __launch_bounds__(256) void kweights(PtrTab P, SegTab S, float* __restrict__ WF,
                                                const void* __restrict__ whh0, int* __restrict__ flag,
                                                int* __restrict__ ghist){
  const bool isbf = detect_bf(whh0);
  if (blockIdx.x == 0){
    if (threadIdx.x == 0) *flag = isbf ? 1 : 0;
    if (threadIdx.x < 195) ghist[threadIdx.x] = 0;
  }
  Seg sg = S.s[blockIdx.x];
  const void* a = P.p[sg.src];
  const void* b = (sg.src2 >= 0) ? P.p[sg.src2] : nullptr;
  for (int i = threadIdx.x; i < sg.n; i += 256){
    float v = ldin(a, sg.soff + i, isbf);
    if (b) v += ldin(b, sg.soff + i, isbf);
    WF[sg.dst + i] = v;
  }
}

// ---------- kernel P: wave-per-batch prep + histogram rank (sort pass 1 absorbed) ----------
__global__ __launch_bounds__(256) void kprep(const void* __restrict__ s,
                                             const void* __restrict__ sh,
                                             const int* __restrict__ hist_len,
                                             const float* __restrict__ WF,
                                             u16* __restrict__ sTx,
                                             int* __restrict__ nar,
                                             u16* __restrict__ xpartT,
                                             const int* __restrict__ flag,
                                             int* __restrict__ ghist,
                                             int* __restrict__ krank){
  __shared__ u16 stage[4][400];
  const bool isbf = (*flag != 0);
  const int t = blockIdx.y;
  const int w = threadIdx.x >> 6;
  const int l = threadIdx.x & 63;
  const int b = blockIdx.x * 4 + w;
  const int hl = hist_len[b];

  const void* base; size_t soff;
  if (t == 0){ base = s; soff = (size_t)b * SROW; }
  else {
    if (hl < 2) return;   // zero-input case via zxp in kfinalM (wave-uniform exit)
    base = sh; soff = ((size_t)b * 2 + ((t == 1) ? 1 : 0)) * SROW;
  }

  float val[7];
  #pragma unroll
  for (int k = 0; k < 7; ++k){
    const int e = k * 64 + l;
    float v = 0.0f;
    if (e < SROW) v = isbf ? bf2f(((const u16*)base)[soff + e]) : ((const float*)base)[soff + e];
    val[k] = v;
  }
  float sOS[7];
  #pragma unroll
  for (int i = 0; i < 7; ++i) sOS[i] = __shfl(val[0], i);

  int n = 0;
  #pragma unroll
  for (int k = 0; k < 7; ++k){
    const int e = k * 64 + l;
    const bool firstf = (e >= 7) && (e < SROW) && ((e - 7) % 6 == 0);
    unsigned long long m = __ballot(firstf && !isnanf32(val[k]));
    n += __popcll(m);
  }

  #pragma unroll
  for (int k = 0; k < 7; ++k){
    const int e = k * 64 + l;
    if (e >= 7 && e < SROW) stage[w][e] = f2bf(isnanf32(val[k]) ? 0.0f : val[k]);
  }

  {
    const int r = l;
    u16 v0 = stage[w][7 + 6 * r],  v1 = stage[w][8 + 6 * r],  v2 = stage[w][9 + 6 * r];
    u16 v3 = stage[w][10 + 6 * r], v4 = stage[w][11 + 6 * r], v5 = stage[w][12 + 6 * r];
    uint4 wv;
    wv.x = (uint)v0 | ((uint)v1 << 16);
    wv.y = (uint)v2 | ((uint)v3 << 16);
    wv.z = (uint)v4 | ((uint)v5 << 16);
    wv.w = 0u;
    *(uint4*)&sTx[((size_t)(t * NB + b) * 64 + r) * 8] = wv;
  }
  if (l == 0){
    nar[t * NB + b] = n;
    const int key = 64 - min(max(n, 0), 64);   // descending n (LPT)
    krank[t * NB + b] = atomicAdd(&ghist[t * 65 + key], 1);
  }

  const float* wos = WF + t * TW + W_WOS;
  const float* bos = WF + t * TW + W_BOS;
  float acc = bos[l];
  #pragma unroll
  for (int i = 0; i < 7; ++i) acc = fmaf(wos[l * 7 + i], sOS[i], acc);
  xpartT[((size_t)(t * NB + b)) * 128 + l] = f2bf(fmaxf(acc, 0.0f));
}

// ---------- sort pass 2/3: scan + atomic-free scatter ----------
__global__ void kscanG(const int* __restrict__ ghist, int* __restrict__ offs, int* __restrict__ cnt){
  const int t = threadIdx.x;
  if (t >= 3) return;
  int acc = 0;
  for (int k = 0; k < 65; ++k){ offs[t * 65 + k] = acc; acc += ghist[t * 65 + k]; }
  cnt[t] = acc;
}
__global__ __launch_bounds__(256) void kscatW(const int* __restrict__ hist_len,
                                              const int* __restrict__ nar,
                                              const int* __restrict__ offs,
                                              const int* __restrict__ krank,
                                              int* __restrict__ idx){
  const int t = blockIdx.y;
  for (int i = threadIdx.x; i < 512; i += 256){
    const int b = blockIdx.x * 512 + i;
    if (t > 0 && hist_len[b] < 2) continue;
    const int key = 64 - min(max(nar[t * NB + b], 0), 64);
    idx[t * NB + offs[t * 65 + key] + krank[t * NB + b]] = b;
  }
}

// ---------- kernel M: barrier-free wave-autonomous LSTM. wave = 16 batches x all 256 gate rows ----------
__global__ __launch_bounds__(256, 1) void kmainM(const int* __restrict__ nar,
                                                 const float* __restrict__ WF,
                                                 const u16* __restrict__ sTx,
                                                 u16* __restrict__ xpartT,
                                                 const int* __restrict__ idx,
                                                 const int* __restrict__ cnt,
                                                 u16* __restrict__ zxp){
  __shared__ u16 hHi[4][16 * 72];   // wave-private regions: no barriers anywhere in main loop
  __shared__ u16 hLo[4][16 * 72];
  __shared__ float zh[64];
  __shared__ float zg[256];
  const int t = blockIdx.y;
  const float* Wt = WF + t * TW;

  // ---- block 0: zero-input trajectory + zxp (t=1,2) ----
  if (blockIdx.x == 0){
    if (t == 0) return;
    const int u = threadIdx.x & 63;
    const int w = threadIdx.x >> 6;
    const int row = w * 64 + u;
    const float* wr = Wt + W_WHH + row * 64;
    const float bsu = Wt[W_BSUM + row];
    if (w == 0) zh[u] = 0.0f;
    float zc = 0.0f;
    __syncthreads();
    for (int step = 0; step < 64; ++step){
      float a0 = 0.0f, a1 = 0.0f, a2 = 0.0f, a3 = 0.0f;
      #pragma unroll
      for (int k = 0; k < 64; k += 4){
        a0 = fmaf(wr[k],     zh[k],     a0);
        a1 = fmaf(wr[k + 1], zh[k + 1], a1);
        a2 = fmaf(wr[k + 2], zh[k + 2], a2);
        a3 = fmaf(wr[k + 3], zh[k + 3], a3);
      }
      zg[row] = bsu + (a0 + a1) + (a2 + a3);
      __syncthreads();
      if (w == 0){
        float gi = zg[u], gf = zg[64 + u], gg = zg[128 + u], go = zg[192 + u];
        zc = sigm(gf) * zc + sigm(gi) * tanh_f(gg);
        zh[u] = sigm(go) * tanh_f(zc);
      }
      __syncthreads();
    }
    if (w == 0){
      float acc = Wt[W_BTS + u];
      const float* wts = Wt + W_WTS + u * 64;
      for (int k = 0; k < 64; ++k) acc = fmaf(wts[k], zh[k], acc);
      zxp[(t - 1) * 128 + 64 + u] = f2bf(fmaxf(acc, 0.0f));
      zxp[(t - 1) * 128 + u]      = f2bf(fmaxf(Wt[W_BOS + u], 0.0f));
    }
    return;
  }

  const int c = cnt[t];
  const int lane = threadIdx.x & 63;
  const int w    = __builtin_amdgcn_readfirstlane((int)(threadIdx.x >> 6));
  const int slot = (blockIdx.x - 1) * 4 + w;      // wave-slot: 16 batches
  if (slot * 16 >= c) return;                     // wave-uniform exit
  const int nlo  = lane & 15;
  const int quad = lane >> 4;

  u16* myHi = &hHi[w][0];
  u16* myLo = &hLo[w][0];
  for (int i = lane; i < 16 * 72; i += 64){ myHi[i] = 0; myLo[i] = 0; }

  // A-fragments: all 256 gate rows as 16 m-tiles (rows mt*16 + nlo), k-frags per §r9 layout
  short8 aW[16][2], aX[16];
  float4v binit[16];
  #pragma unroll
  for (int mt = 0; mt < 16; ++mt){
    const int mrow = mt * 16 + nlo;
    const float* wr = Wt + W_WHH + mrow * 64;
    #pragma unroll
    for (int f = 0; f < 2; ++f){
      const int k0 = f * 32 + quad * 8;
      short8 a;
      #pragma unroll
      for (int j = 0; j < 8; ++j) a[j] = (short)f2bf(wr[k0 + j]);
      aW[mt][f] = a;
    }
    const float* wi = Wt + W_WIH + mrow * 6;
    short8 ax = {0, 0, 0, 0, 0, 0, 0, 0};
    if (quad == 0){
      #pragma unroll
      for (int j = 0; j < 6; ++j) ax[j] = (short)f2bf(wi[j]);
    }
    aX[mt] = ax;
    binit[mt] = *(const float4v*)(Wt + W_BSUM + mt * 16 + quad * 4);
  }

  const int pos = min(slot * 16 + nlo, c - 1);    // clamp replaces pad
  const int bb = idx[t * NB + pos];
  const int n_l = nar[t * NB + bb];
  const u16* sB = sTx + (size_t)(t * NB + bb) * 512;
  int nmax = n_l;
  #pragma unroll
  for (int o = 1; o < 16; o <<= 1) nmax = max(nmax, __shfl_xor(nmax, o));

  float c_st[4][4], h_st[4][4];
  #pragma unroll
  for (int j = 0; j < 4; ++j)
    #pragma unroll
    for (int r = 0; r < 4; ++r){ c_st[j][r] = 0.0f; h_st[j][r] = 0.0f; }

  short8 xcur = {0, 0, 0, 0, 0, 0, 0, 0}, xnxt;
  if (lane < 16) xcur = *(const short8*)sB;

  for (int step = 0; step < nmax; ++step){
    xnxt = (short8){0, 0, 0, 0, 0, 0, 0, 0};
    const int ns = min(step + 1, 63);
    if (lane < 16) xnxt = *(const short8*)(sB + (size_t)ns * 8);

    const int hb = nlo * 72 + quad * 8;
    short8 h0 = *(const short8*)&myHi[hb];
    short8 h1 = *(const short8*)&myHi[hb + 32];
    short8 l0 = *(const short8*)&myLo[hb];
    short8 l1 = *(const short8*)&myLo[hb + 32];

    float4v acc[16];
    #pragma unroll
    for (int mt = 0; mt < 16; ++mt){
      float4v a = binit[mt];
      a = MFMA16(aX[mt], xcur, a);     // identical accumulation order to r9/r11
      a = MFMA16(aW[mt][0], h0, a);
      a = MFMA16(aW[mt][1], h1, a);
      a = MFMA16(aW[mt][0], l0, a);
      a = MFMA16(aW[mt][1], l1, a);
      acc[mt] = a;
    }

    const bool v = (step < n_l);
    #pragma unroll
    for (int j = 0; j < 4; ++j){       // unit group: u = j*16 + quad*4 + r, batch = nlo
      u16 hb4[4], lb4[4];
      #pragma unroll
      for (int r = 0; r < 4; ++r){
        float gi = acc[j][r], gf = acc[4 + j][r], gg = acc[8 + j][r], go = acc[12 + j][r];
        float cn = sigm(gf) * c_st[j][r] + sigm(gi) * tanh_f(gg);
        float hn = sigm(go) * tanh_f(cn);
        c_st[j][r] = v ? cn : c_st[j][r];
        h_st[j][r] = v ? hn : h_st[j][r];
        u16 hi = f2bf(h_st[j][r]);
        float lo = h_st[j][r] - bf2f(hi);
        hb4[r] = hi; lb4[r] = f2bf(lo);
      }
      const int off = nlo * 72 + j * 16 + quad * 4;
      uint2 hw, lw;
      hw.x = (uint)hb4[0] | ((uint)hb4[1] << 16);
      hw.y = (uint)hb4[2] | ((uint)hb4[3] << 16);
      lw.x = (uint)lb4[0] | ((uint)lb4[1] << 16);
      lw.y = (uint)lb4[2] | ((uint)lb4[3] << 16);
      *(uint2*)&myHi[off] = hw;
      *(uint2*)&myLo[off] = lw;
    }
    xcur = xnxt;
    // no barrier: wave-private LDS, in-order DS per wave
  }

  // xTS epilogue: WTS (64x64) as 4 m-tiles
  const int hb = nlo * 72 + quad * 8;
  short8 h0 = *(const short8*)&myHi[hb];
  short8 h1 = *(const short8*)&myHi[hb + 32];
  short8 l0 = *(const short8*)&myLo[hb];
  short8 l1 = *(const short8*)&myLo[hb + 32];
  #pragma unroll
  for (int mt = 0; mt < 4; ++mt){
    short8 aT0, aT1;
    {
      const float* wr = Wt + W_WTS + (mt * 16 + nlo) * 64 + quad * 8;
      #pragma unroll
      for (int j = 0; j < 8; ++j) aT0[j] = (short)f2bf(wr[j]);
      #pragma unroll
      for (int j = 0; j < 8; ++j) aT1[j] = (short)f2bf(wr[32 + j]);
    }
    float4v a = *(const float4v*)(Wt + W_BTS + mt * 16 + quad * 4);
    a = MFMA16(aT0, h0, a);
    a = MFMA16(aT1, h1, a);
    a = MFMA16(aT0, l0, a);
    a = MFMA16(aT1, l1, a);
    u16 o4[4];
    #pragma unroll
    for (int r = 0; r < 4; ++r) o4[r] = f2bf(fmaxf(a[r], 0.0f));
    size_t oidx = ((size_t)(t * NB + bb)) * 128 + 64 + mt * 16 + quad * 4;
    uint2 wv;
    wv.x = (uint)o4[0] | ((uint)o4[1] << 16);
    wv.y = (uint)o4[2] | ((uint)o4[3] << 16);
    *(uint2*)&xpartT[oidx] = wv;
  }
}

// ---------- kernel F: outer LSTM via MFMA (3 steps) + MLP; 32-batch tiles ----------
__global__ __launch_bounds__(256) void kfinalM(const float* __restrict__ WF,
                                               const u16* __restrict__ xpartT,
                                               const u16* __restrict__ zxp,
                                               const int* __restrict__ hist_len,
                                               void* __restrict__ out,
                                               const int* __restrict__ flag){
  __shared__ u16 hHi[32 * 72];
  __shared__ u16 hLo[32 * 72];
  __shared__ float x1T[32 * 68];
  const bool isbf = (*flag != 0);
  const int b0   = blockIdx.x * 32;
  const int lane = threadIdx.x & 63;
  const int q    = __builtin_amdgcn_readfirstlane((int)(threadIdx.x >> 6));
  const int nlo  = lane & 15;
  const int quad = lane >> 4;

  for (int i = threadIdx.x; i < 32 * 72; i += 256){ hHi[i] = 0; hLo[i] = 0; }

  const float* WO = WF + W_OUT;
  int hl2[2];
  #pragma unroll
  for (int nt = 0; nt < 2; ++nt) hl2[nt] = hist_len[b0 + nt * 16 + nlo];

  short8 aI[4][4], aH[4][2];
  float4v bi4[4];
  #pragma unroll
  for (int g = 0; g < 4; ++g){
    const int mrow = g * 64 + q * 16 + nlo;
    #pragma unroll
    for (int f = 0; f < 4; ++f){
      const float* w = WO + WO_WIHO + mrow * 128 + f * 32 + quad * 8;
      short8 a;
      #pragma unroll
      for (int j = 0; j < 8; ++j) a[j] = (short)f2bf(w[j]);
      aI[g][f] = a;
    }
    #pragma unroll
    for (int f = 0; f < 2; ++f){
      const float* w = WO + WO_WHHO + mrow * 64 + f * 32 + quad * 8;
      short8 a;
      #pragma unroll
      for (int j = 0; j < 8; ++j) a[j] = (short)f2bf(w[j]);
      aH[g][f] = a;
    }
    bi4[g] = *(const float4v*)(WO + WO_BSUM + g * 64 + q * 16 + quad * 4);
  }

  float c_st[2][4], h_st[2][4];
  #pragma unroll
  for (int nt = 0; nt < 2; ++nt)
    #pragma unroll
    for (int r = 0; r < 4; ++r){ c_st[nt][r] = 0.0f; h_st[nt][r] = 0.0f; }
  __syncthreads();

  for (int p = 0; p < 3; ++p){
    float4v acc[4][2];
    #pragma unroll
    for (int nt = 0; nt < 2; ++nt){
      const int bb = b0 + nt * 16 + nlo;
      const int tt = 2 - ((p - hl2[nt] + 2) % 3);
      const u16* xb = (tt > 0 && hl2[nt] < 2) ? (zxp + (tt - 1) * 128)
                                              : xpartT + ((size_t)(tt * NB + bb)) * 128;
      short8 xf[4];
      #pragma unroll
      for (int f = 0; f < 4; ++f) xf[f] = *(const short8*)(xb + f * 32 + quad * 8);
      const int hb = (nt * 16 + nlo) * 72 + quad * 8;
      short8 h0 = *(const short8*)&hHi[hb];
      short8 h1 = *(const short8*)&hHi[hb + 32];
      short8 l0 = *(const short8*)&hLo[hb];
      short8 l1 = *(const short8*)&hLo[hb + 32];
      #pragma unroll
      for (int g = 0; g < 4; ++g){
        float4v a = bi4[g];
        #pragma unroll
        for (int f = 0; f < 4; ++f) a = MFMA16(aI[g][f], xf[f], a);
        a = MFMA16(aH[g][0], h0, a);
        a = MFMA16(aH[g][1], h1, a);
        a = MFMA16(aH[g][0], l0, a);
        a = MFMA16(aH[g][1], l1, a);
        acc[g][nt] = a;
      }
    }
    __syncthreads();
    #pragma unroll
    for (int nt = 0; nt < 2; ++nt){
      const bool v = (p <= hl2[nt]);
      u16 hb4[4], lb4[4];
      #pragma unroll
      for (int r = 0; r < 4; ++r){
        float gi = acc[0][nt][r], gf = acc[1][nt][r], gg = acc[2][nt][r], go = acc[3][nt][r];
        float cn = sigm(gf) * c_st[nt][r] + sigm(gi) * tanh_f(gg);
        float hn = sigm(go) * tanh_f(cn);
        c_st[nt][r] = v ? cn : c_st[nt][r];
        h_st[nt][r] = v ? hn : h_st[nt][r];
        u16 hi = f2bf(h_st[nt][r]);
        float lo = h_st[nt][r] - bf2f(hi);
        hb4[r] = hi; lb4[r] = f2bf(lo);
      }
      const int off = (nt * 16 + nlo) * 72 + q * 16 + quad * 4;
      uint2 hw, lw;
      hw.x = (uint)hb4[0] | ((uint)hb4[1] << 16);
      hw.y = (uint)hb4[2] | ((uint)hb4[3] << 16);
      lw.x = (uint)lb4[0] | ((uint)lb4[1] << 16);
      lw.y = (uint)lb4[2] | ((uint)lb4[3] << 16);
      *(uint2*)&hHi[off] = hw;
      *(uint2*)&hLo[off] = lw;
    }
    __syncthreads();
  }

  short8 a1[2];
  #pragma unroll
  for (int f = 0; f < 2; ++f){
    const float* w = WO + WO_W1 + (q * 16 + nlo) * 64 + f * 32 + quad * 8;
    short8 a;
    #pragma unroll
    for (int j = 0; j < 8; ++j) a[j] = (short)f2bf(w[j]);
    a1[f] = a;
  }
  float4v b1v = *(const float4v*)(WO + WO_B1 + q * 16 + quad * 4);
  #pragma unroll
  for (int nt = 0; nt < 2; ++nt){
    const int hb = (nt * 16 + nlo) * 72 + quad * 8;
    float4v a = b1v;
    a = MFMA16(a1[0], *(const short8*)&hHi[hb], a);
    a = MFMA16(a1[1], *(const short8*)&hHi[hb + 32], a);
    a = MFMA16(a1[0], *(const short8*)&hLo[hb], a);
    a = MFMA16(a1[1], *(const short8*)&hLo[hb + 32], a);
    float4v rv;
    #pragma unroll
    for (int r = 0; r < 4; ++r) rv[r] = fmaxf(a[r], 0.0f);
    *(float4v*)&x1T[(nt * 16 + nlo) * 68 + q * 16 + quad * 4] = rv;
  }
  __syncthreads();

  const int bloc = threadIdx.x >> 3;       // 0..31
  const int r0 = threadIdx.x & 7;
  const float* w2 = WO + WO_W2;
  const float* b2 = WO + WO_B2;
  for (int r = r0; r < 9; r += 8){
    float acc = b2[r];
    const float* wr = w2 + r * 64;
    #pragma unroll
    for (int k = 0; k < 64; ++k) acc = fmaf(wr[k], x1T[bloc * 68 + k], acc);
    if (isbf) ((u16*)out)[(size_t)(b0 + bloc) * 9 + r] = f2bf(acc);
    else      ((float*)out)[(size_t)(b0 + bloc) * 9 + r] = acc;
  }
}

extern "C" void kernel_launch(void* const* d_in, const int* in_sizes, int n_in,
                              void* d_out, int out_size, void* d_ws, size_t ws_size,
                              hipStream_t stream){
  char* ws = (char*)d_ws;
  float* WF = (float*)ws;
  size_t off = ((size_t)WF_TOTAL * 4 + 255) & ~(size_t)255;
  u16* sTx = (u16*)(ws + off);    off += (size_t)3 * NB * 512 * 2;
  u16* xpartT = (u16*)(ws + off); off += (size_t)3 * NB * 128 * 2;
  int* nar = (int*)(ws + off);    off += (size_t)3 * NB * 4;
  int* flag = (int*)(ws + off);   off += 256;
  int* cnt  = (int*)(ws + off);   off += 256;
  int* ghist = (int*)(ws + off);  off += 3 * 65 * 4 + 64;
  int* offs = (int*)(ws + off);   off += 3 * 65 * 4 + 64;
  int* idx  = (int*)(ws + off);   off += (size_t)3 * NB * 4;
  int* krank = (int*)(ws + off);  off += (size_t)3 * NB * 4;
  u16* zxp  = (u16*)(ws + off);   off += 2 * 128 * 2;

  PtrTab P;
  for (int i = 0; i < 36; ++i) P.p[i] = d_in[i];

  SegTab S;
  int si = 0;
  for (int t = 0; t < 3; ++t){
    int base = 4 + 8 * t;
    int d = t * TW;
    S.s[si++] = { base + 2, -1,       0,     d + W_WIH,         1536 };
    S.s[si++] = { base + 3, -1,       0,     d + W_WHH,         8192 };
    S.s[si++] = { base + 3, -1,       8192,  d + W_WHH + 8192,  8192 };
    S.s[si++] = { base + 4, base + 5, 0,     d + W_BSUM,        256  };
    S.s[si++] = { base + 6, -1,       0,     d + W_WTS,         4096 };
    S.s[si++] = { base + 7, -1,       0,     d + W_BTS,         64   };
    S.s[si++] = { base + 0, -1,       0,     d + W_WOS,         448  };
    S.s[si++] = { base + 1, -1,       0,     d + W_BOS,         64   };
  }
  {
    int O = W_OUT;
    for (int k = 0; k < 4; ++k)
      S.s[si++] = { 28, -1, k * 8192, O + WO_WIHO + k * 8192, 8192 };
    S.s[si++] = { 29, -1, 0,    O + WO_WHHO,        8192 };
    S.s[si++] = { 29, -1, 8192, O + WO_WHHO + 8192, 8192 };
    S.s[si++] = { 30, 31, 0,    O + WO_BSUM,        256  };
    S.s[si++] = { 32, -1, 0,    O + WO_W1,          4096 };
    S.s[si++] = { 33, -1, 0,    O + WO_B1,          64   };
    S.s[si++] = { 34, -1, 0,    O + WO_W2,          576  };
    S.s[si++] = { 35, -1, 0,    O + WO_B2,          9    };
  }

  const int* hl_ptr = (const int*)d_in[3];

  kweights<<<dim3(35), 256, 0, stream>>>(P, S, WF, d_in[7], flag, ghist);
  kprep<<<dim3(NB / 4, 3), 256, 0, stream>>>(d_in[0], d_in[1], hl_ptr, WF, sTx, nar, xpartT, flag, ghist, krank);
  kscanG<<<dim3(1), 64, 0, stream>>>(ghist, offs, cnt);
  kscatW<<<dim3(16, 3), 256, 0, stream>>>(hl_ptr, nar, offs, krank, idx);
  kmainM<<<dim3(129, 3), 256, 0, stream>>>(nar, WF, sTx, xpartT, idx, cnt, zxp);
  kfinalM<<<dim3(NB / 32), 256, 0, stream>>>(WF, xpartT, zxp, hl_ptr, d_out, flag);
}

// Round 13
// 372.382 us; speedup vs baseline: 1.2921x; 1.2921x over previous
//
#include <hip/hip_runtime.h>
#include <hip/hip_bf16.h>

#define NB 8192
#define SROW 391

// ---- weight ws layout (floats) ----
#define TW      22848
#define W_WIH   0
#define W_WHH   1536
#define W_BSUM  17920
#define W_WTS   18176
#define W_BTS   22272
#define W_WOS   22336
#define W_BOS   22784
#define W_OUT   68544
#define WO_WIHO 0
#define WO_WHHO 32768
#define WO_BSUM 49152
#define WO_W1   49408
#define WO_B1   53504
#define WO_W2   53568
#define WO_B2   54144
#define WF_TOTAL 122697

typedef unsigned short u16;
typedef __attribute__((ext_vector_type(8))) short short8;
typedef __attribute__((ext_vector_type(4))) float float4v;

#define MFMA16(a, b, c) __builtin_amdgcn_mfma_f32_16x16x32_bf16((a), (b), (c), 0, 0, 0)

__device__ __forceinline__ float bf2f(u16 u){ return __uint_as_float(((unsigned)u) << 16); }
__device__ __forceinline__ u16 f2bf(float f){
  unsigned x = __float_as_uint(f);
  unsigned r = (x + 0x7FFFu + ((x >> 16) & 1u)) >> 16;   // RNE
  return (u16)r;
}
__device__ __forceinline__ bool isnanf32(float f){
  unsigned x = __float_as_uint(f);
  return (x & 0x7FFFFFFFu) > 0x7F800000u;
}
__device__ __forceinline__ float ldin(const void* p, size_t i, bool isbf){
  if (isbf) return bf2f(((const u16*)p)[i]);
  return ((const float*)p)[i];
}
__device__ __forceinline__ float sigm(float x){ return __fdividef(1.0f, 1.0f + __expf(-x)); }
__device__ __forceinline__ float tanh_f(float x){ return __fdividef(2.0f, 1.0f + __expf(-2.0f * x)) - 1.0f; }

__device__ __forceinline__ bool detect_bf(const void* whh0){
  const u16* u = (const u16*)whh0;
  const int l = threadIdx.x & 63;
  int e = (u[2 * l] >> 7) & 0xFF;
  unsigned long long m = __ballot(e >= 100 && e <= 141);
  return __popcll(m) >= 32;
}

struct Seg { int src; int src2; int soff; int dst; int n; };
struct SegTab { Seg s[35]; };
struct PtrTab { const void* p[36]; };

// ---------- kernel W: weights -> fp32; publish dtype flag; zero histogram ----------
__global__ __launch_bounds__(256) void kweights(PtrTab P, SegTab S, float* __restrict__ WF,
                                                const void* __restrict__ whh0, int* __restrict__ flag,
                                                int* __restrict__ ghist){
  const bool isbf = detect_bf(whh0);
  if (blockIdx.x == 0){
    if (threadIdx.x == 0) *flag = isbf ? 1 : 0;
    if (threadIdx.x < 195) ghist[threadIdx.x] = 0;
  }
  Seg sg = S.s[blockIdx.x];
  const void* a = P.p[sg.src];
  const void* b = (sg.src2 >= 0) ? P.p[sg.src2] : nullptr;
  for (int i = threadIdx.x; i < sg.n; i += 256){
    float v = ldin(a, sg.soff + i, isbf);
    if (b) v += ldin(b, sg.soff + i, isbf);
    WF[sg.dst + i] = v;
  }
}

// ---------- kernel P: wave-per-batch prep + histogram rank (sort pass 1 absorbed) ----------
__global__ __launch_bounds__(256) void kprep(const void* __restrict__ s,
                                             const void* __restrict__ sh,
                                             const int* __restrict__ hist_len,
                                             const float* __restrict__ WF,
                                             u16* __restrict__ sTx,
                                             int* __restrict__ nar,
                                             u16* __restrict__ xpartT,
                                             const int* __restrict__ flag,
                                             int* __restrict__ ghist,
                                             int* __restrict__ krank){
  __shared__ u16 stage[4][400];
  const bool isbf = (*flag != 0);
  const int t = blockIdx.y;
  const int w = threadIdx.x >> 6;
  const int l = threadIdx.x & 63;
  const int b = blockIdx.x * 4 + w;
  const int hl = hist_len[b];

  const void* base; size_t soff;
  if (t == 0){ base = s; soff = (size_t)b * SROW; }
  else {
    if (hl < 2) return;   // zero-input case via zxp in kfinalM (wave-uniform exit)
    base = sh; soff = ((size_t)b * 2 + ((t == 1) ? 1 : 0)) * SROW;
  }

  float val[7];
  #pragma unroll
  for (int k = 0; k < 7; ++k){
    const int e = k * 64 + l;
    float v = 0.0f;
    if (e < SROW) v = isbf ? bf2f(((const u16*)base)[soff + e]) : ((const float*)base)[soff + e];
    val[k] = v;
  }
  float sOS[7];
  #pragma unroll
  for (int i = 0; i < 7; ++i) sOS[i] = __shfl(val[0], i);

  int n = 0;
  #pragma unroll
  for (int k = 0; k < 7; ++k){
    const int e = k * 64 + l;
    const bool firstf = (e >= 7) && (e < SROW) && ((e - 7) % 6 == 0);
    unsigned long long m = __ballot(firstf && !isnanf32(val[k]));
    n += __popcll(m);
  }

  #pragma unroll
  for (int k = 0; k < 7; ++k){
    const int e = k * 64 + l;
    if (e >= 7 && e < SROW) stage[w][e] = f2bf(isnanf32(val[k]) ? 0.0f : val[k]);
  }

  {
    const int r = l;
    u16 v0 = stage[w][7 + 6 * r],  v1 = stage[w][8 + 6 * r],  v2 = stage[w][9 + 6 * r];
    u16 v3 = stage[w][10 + 6 * r], v4 = stage[w][11 + 6 * r], v5 = stage[w][12 + 6 * r];
    uint4 wv;
    wv.x = (uint)v0 | ((uint)v1 << 16);
    wv.y = (uint)v2 | ((uint)v3 << 16);
    wv.z = (uint)v4 | ((uint)v5 << 16);
    wv.w = 0u;
    *(uint4*)&sTx[((size_t)(t * NB + b) * 64 + r) * 8] = wv;
  }
  if (l == 0){
    nar[t * NB + b] = n;
    const int key = 64 - min(max(n, 0), 64);   // descending n (LPT)
    krank[t * NB + b] = atomicAdd(&ghist[t * 65 + key], 1);
  }

  const float* wos = WF + t * TW + W_WOS;
  const float* bos = WF + t * TW + W_BOS;
  float acc = bos[l];
  #pragma unroll
  for (int i = 0; i < 7; ++i) acc = fmaf(wos[l * 7 + i], sOS[i], acc);
  xpartT[((size_t)(t * NB + b)) * 128 + l] = f2bf(fmaxf(acc, 0.0f));
}

// ---------- scatter with local scan (scan launch folded in) ----------
__global__ __launch_bounds__(256) void kscatW(const int* __restrict__ hist_len,
                                              const int* __restrict__ nar,
                                              const int* __restrict__ ghist,
                                              const int* __restrict__ krank,
                                              int* __restrict__ idx,
                                              int* __restrict__ cnt){
  __shared__ int o[65];
  const int t = blockIdx.y;
  if (threadIdx.x == 0){
    int acc = 0;
    for (int k = 0; k < 65; ++k){ o[k] = acc; acc += ghist[t * 65 + k]; }
    if (blockIdx.x == 0) cnt[t] = acc;
  }
  __syncthreads();
  for (int i = threadIdx.x; i < 512; i += 256){
    const int b = blockIdx.x * 512 + i;
    if (t > 0 && hist_len[b] < 2) continue;
    const int key = 64 - min(max(nar[t * NB + b], 0), 64);
    idx[t * NB + o[key] + krank[t * NB + b]] = b;
  }
}

// ---------- kernel M: r11 structure, 16-batch tiles (nt loop = 1): max co-residency ----------
__global__ __launch_bounds__(256) void kmainM(const int* __restrict__ nar,
                                              const float* __restrict__ WF,
                                              const u16* __restrict__ sTx,
                                              u16* __restrict__ xpartT,
                                              const int* __restrict__ idx,
                                              const int* __restrict__ cnt,
                                              u16* __restrict__ zxp){
  __shared__ u16 hHi[2][16 * 72];
  __shared__ u16 hLo[2][16 * 72];
  __shared__ float zh[64];
  __shared__ float zg[256];
  const int t = blockIdx.y;
  const float* Wt = WF + t * TW;

  // ---- block 0: zero-input trajectory + zxp (t=1,2) ----
  if (blockIdx.x == 0){
    if (t == 0) return;
    const int u = threadIdx.x & 63;
    const int w = threadIdx.x >> 6;
    const int row = w * 64 + u;
    const float* wr = Wt + W_WHH + row * 64;
    const float bsu = Wt[W_BSUM + row];
    if (w == 0) zh[u] = 0.0f;
    float zc = 0.0f;
    __syncthreads();
    for (int step = 0; step < 64; ++step){
      float a0 = 0.0f, a1 = 0.0f, a2 = 0.0f, a3 = 0.0f;
      #pragma unroll
      for (int k = 0; k < 64; k += 4){
        a0 = fmaf(wr[k],     zh[k],     a0);
        a1 = fmaf(wr[k + 1], zh[k + 1], a1);
        a2 = fmaf(wr[k + 2], zh[k + 2], a2);
        a3 = fmaf(wr[k + 3], zh[k + 3], a3);
      }
      zg[row] = bsu + (a0 + a1) + (a2 + a3);
      __syncthreads();
      if (w == 0){
        float gi = zg[u], gf = zg[64 + u], gg = zg[128 + u], go = zg[192 + u];
        zc = sigm(gf) * zc + sigm(gi) * tanh_f(gg);
        zh[u] = sigm(go) * tanh_f(zc);
      }
      __syncthreads();
    }
    if (w == 0){
      float acc = Wt[W_BTS + u];
      const float* wts = Wt + W_WTS + u * 64;
      for (int k = 0; k < 64; ++k) acc = fmaf(wts[k], zh[k], acc);
      zxp[(t - 1) * 128 + 64 + u] = f2bf(fmaxf(acc, 0.0f));
      zxp[(t - 1) * 128 + u]      = f2bf(fmaxf(Wt[W_BOS + u], 0.0f));
    }
    return;
  }

  const int c = cnt[t];
  const int bx = blockIdx.x - 1;
  if (bx * 16 >= c) return;

  const int lane = threadIdx.x & 63;
  const int q    = __builtin_amdgcn_readfirstlane((int)(threadIdx.x >> 6));
  const int nlo  = lane & 15;
  const int quad = lane >> 4;

  for (int i = threadIdx.x; i < 16 * 72; i += 256){ hHi[0][i] = 0; hLo[0][i] = 0; }

  short8 aW[4][2], aX[4];
  float4v binit[4];
  #pragma unroll
  for (int g = 0; g < 4; ++g){
    const int mrow = g * 64 + q * 16 + nlo;
    const float* wr = Wt + W_WHH + mrow * 64;
    #pragma unroll
    for (int f = 0; f < 2; ++f){
      const int k0 = f * 32 + quad * 8;
      short8 a;
      #pragma unroll
      for (int j = 0; j < 8; ++j) a[j] = (short)f2bf(wr[k0 + j]);
      aW[g][f] = a;
    }
    const float* wi = Wt + W_WIH + mrow * 6;
    short8 ax = {0, 0, 0, 0, 0, 0, 0, 0};
    if (quad == 0){
      #pragma unroll
      for (int j = 0; j < 6; ++j) ax[j] = (short)f2bf(wi[j]);
    }
    aX[g] = ax;
    binit[g] = *(const float4v*)(Wt + W_BSUM + g * 64 + q * 16 + quad * 4);
  }

  const int pos = min(bx * 16 + nlo, c - 1);   // clamp replaces pad
  const int bb = idx[t * NB + pos];
  const int n_l = nar[t * NB + bb];
  const u16* sB = sTx + (size_t)(t * NB + bb) * 512;
  int nmax = n_l;
  #pragma unroll
  for (int o = 1; o < 16; o <<= 1) nmax = max(nmax, __shfl_xor(nmax, o));

  float c_st[4], h_st[4];
  #pragma unroll
  for (int r = 0; r < 4; ++r){ c_st[r] = 0.0f; h_st[r] = 0.0f; }

  short8 xcur = {0, 0, 0, 0, 0, 0, 0, 0}, xnxt;
  if (lane < 16) xcur = *(const short8*)sB;

  __syncthreads();

  for (int step = 0; step < nmax; ++step){
    xnxt = (short8){0, 0, 0, 0, 0, 0, 0, 0};
    const int ns = min(step + 1, 63);
    if (lane < 16) xnxt = *(const short8*)(sB + (size_t)ns * 8);

    const u16* rHi = hHi[step & 1];
    const u16* rLo = hLo[step & 1];
    u16* wHi = hHi[(step + 1) & 1];
    u16* wLo = hLo[(step + 1) & 1];

    const int hb = nlo * 72 + quad * 8;
    short8 h0 = *(const short8*)&rHi[hb];
    short8 h1 = *(const short8*)&rHi[hb + 32];
    short8 l0 = *(const short8*)&rLo[hb];
    short8 l1 = *(const short8*)&rLo[hb + 32];

    float4v acc[4];
    #pragma unroll
    for (int g = 0; g < 4; ++g){
      float4v a = binit[g];
      a = MFMA16(aX[g], xcur, a);     // identical accumulation order to r9/r11
      a = MFMA16(aW[g][0], h0, a);
      a = MFMA16(aW[g][1], h1, a);
      a = MFMA16(aW[g][0], l0, a);
      a = MFMA16(aW[g][1], l1, a);
      acc[g] = a;
    }

    const bool v = (step < n_l);
    u16 hb4[4], lb4[4];
    #pragma unroll
    for (int r = 0; r < 4; ++r){
      float gi = acc[0][r], gf = acc[1][r], gg = acc[2][r], go = acc[3][r];
      float cn = sigm(gf) * c_st[r] + sigm(gi) * tanh_f(gg);
      float hn = sigm(go) * tanh_f(cn);
      c_st[r] = v ? cn : c_st[r];
      h_st[r] = v ? hn : h_st[r];
      u16 hi = f2bf(h_st[r]);
      float lo = h_st[r] - bf2f(hi);
      hb4[r] = hi; lb4[r] = f2bf(lo);
    }
    const int off = nlo * 72 + q * 16 + quad * 4;
    uint2 hw, lw;
    hw.x = (uint)hb4[0] | ((uint)hb4[1] << 16);
    hw.y = (uint)hb4[2] | ((uint)hb4[3] << 16);
    lw.x = (uint)lb4[0] | ((uint)lb4[1] << 16);
    lw.y = (uint)lb4[2] | ((uint)lb4[3] << 16);
    *(uint2*)&wHi[off] = hw;
    *(uint2*)&wLo[off] = lw;

    xcur = xnxt;
    __syncthreads();   // single barrier: dbuf removes WAR hazard
  }

  // xTS epilogue from final h buffer
  const u16* fHi = hHi[nmax & 1];
  const u16* fLo = hLo[nmax & 1];
  short8 aT[2];
  #pragma unroll
  for (int f = 0; f < 2; ++f){
    const float* wr = Wt + W_WTS + (q * 16 + nlo) * 64 + f * 32 + quad * 8;
    short8 a;
    #pragma unroll
    for (int j = 0; j < 8; ++j) a[j] = (short)f2bf(wr[j]);
    aT[f] = a;
  }
  float4v btsv = *(const float4v*)(Wt + W_BTS + q * 16 + quad * 4);
  {
    const int hb = nlo * 72 + quad * 8;
    float4v a = btsv;
    a = MFMA16(aT[0], *(const short8*)&fHi[hb], a);
    a = MFMA16(aT[1], *(const short8*)&fHi[hb + 32], a);
    a = MFMA16(aT[0], *(const short8*)&fLo[hb], a);
    a = MFMA16(aT[1], *(const short8*)&fLo[hb + 32], a);
    u16 o4[4];
    #pragma unroll
    for (int r = 0; r < 4; ++r) o4[r] = f2bf(fmaxf(a[r], 0.0f));
    size_t oidx = ((size_t)(t * NB + bb)) * 128 + 64 + q * 16 + quad * 4;
    uint2 wv;
    wv.x = (uint)o4[0] | ((uint)o4[1] << 16);
    wv.y = (uint)o4[2] | ((uint)o4[3] << 16);
    *(uint2*)&xpartT[oidx] = wv;
  }
}

// ---------- kernel F: outer LSTM via MFMA (3 steps) + MLP; 32-batch tiles ----------
__global__ __launch_bounds__(256) void kfinalM(const float* __restrict__ WF,
                                               const u16* __restrict__ xpartT,
                                               const u16* __restrict__ zxp,
                                               const int* __restrict__ hist_len,
                                               void* __restrict__ out,
                                               const int* __restrict__ flag){
  __shared__ u16 hHi[32 * 72];
  __shared__ u16 hLo[32 * 72];
  __shared__ float x1T[32 * 68];
  const bool isbf = (*flag != 0);
  const int b0   = blockIdx.x * 32;
  const int lane = threadIdx.x & 63;
  const int q    = __builtin_amdgcn_readfirstlane((int)(threadIdx.x >> 6));
  const int nlo  = lane & 15;
  const int quad = lane >> 4;

  for (int i = threadIdx.x; i < 32 * 72; i += 256){ hHi[i] = 0; hLo[i] = 0; }

  const float* WO = WF + W_OUT;
  int hl2[2];
  #pragma unroll
  for (int nt = 0; nt < 2; ++nt) hl2[nt] = hist_len[b0 + nt * 16 + nlo];

  short8 aI[4][4], aH[4][2];
  float4v bi4[4];
  #pragma unroll
  for (int g = 0; g < 4; ++g){
    const int mrow = g * 64 + q * 16 + nlo;
    #pragma unroll
    for (int f = 0; f < 4; ++f){
      const float* w = WO + WO_WIHO + mrow * 128 + f * 32 + quad * 8;
      short8 a;
      #pragma unroll
      for (int j = 0; j < 8; ++j) a[j] = (short)f2bf(w[j]);
      aI[g][f] = a;
    }
    #pragma unroll
    for (int f = 0; f < 2; ++f){
      const float* w = WO + WO_WHHO + mrow * 64 + f * 32 + quad * 8;
      short8 a;
      #pragma unroll
      for (int j = 0; j < 8; ++j) a[j] = (short)f2bf(w[j]);
      aH[g][f] = a;
    }
    bi4[g] = *(const float4v*)(WO + WO_BSUM + g * 64 + q * 16 + quad * 4);
  }

  float c_st[2][4], h_st[2][4];
  #pragma unroll
  for (int nt = 0; nt < 2; ++nt)
    #pragma unroll
    for (int r = 0; r < 4; ++r){ c_st[nt][r] = 0.0f; h_st[nt][r] = 0.0f; }
  __syncthreads();

  for (int p = 0; p < 3; ++p){
    float4v acc[4][2];
    #pragma unroll
    for (int nt = 0; nt < 2; ++nt){
      const int bb = b0 + nt * 16 + nlo;
      const int tt = 2 - ((p - hl2[nt] + 2) % 3);
      const u16* xb = (tt > 0 && hl2[nt] < 2) ? (zxp + (tt - 1) * 128)
                                              : xpartT + ((size_t)(tt * NB + bb)) * 128;
      short8 xf[4];
      #pragma unroll
      for (int f = 0; f < 4; ++f) xf[f] = *(const short8*)(xb + f * 32 + quad * 8);
      const int hb = (nt * 16 + nlo) * 72 + quad * 8;
      short8 h0 = *(const short8*)&hHi[hb];
      short8 h1 = *(const short8*)&hHi[hb + 32];
      short8 l0 = *(const short8*)&hLo[hb];
      short8 l1 = *(const short8*)&hLo[hb + 32];
      #pragma unroll
      for (int g = 0; g < 4; ++g){
        float4v a = bi4[g];
        #pragma unroll
        for (int f = 0; f < 4; ++f) a = MFMA16(aI[g][f], xf[f], a);
        a = MFMA16(aH[g][0], h0, a);
        a = MFMA16(aH[g][1], h1, a);
        a = MFMA16(aH[g][0], l0, a);
        a = MFMA16(aH[g][1], l1, a);
        acc[g][nt] = a;
      }
    }
    __syncthreads();
    #pragma unroll
    for (int nt = 0; nt < 2; ++nt){
      const bool v = (p <= hl2[nt]);
      u16 hb4[4], lb4[4];
      #pragma unroll
      for (int r = 0; r < 4; ++r){
        float gi = acc[0][nt][r], gf = acc[1][nt][r], gg = acc[2][nt][r], go = acc[3][nt][r];
        float cn = sigm(gf) * c_st[nt][r] + sigm(gi) * tanh_f(gg);
        float hn = sigm(go) * tanh_f(cn);
        c_st[nt][r] = v ? cn : c_st[nt][r];
        h_st[nt][r] = v ? hn : h_st[nt][r];
        u16 hi = f2bf(h_st[nt][r]);
        float lo = h_st[nt][r] - bf2f(hi);
        hb4[r] = hi; lb4[r] = f2bf(lo);
      }
      const int off = (nt * 16 + nlo) * 72 + q * 16 + quad * 4;
      uint2 hw, lw;
      hw.x = (uint)hb4[0] | ((uint)hb4[1] << 16);
      hw.y = (uint)hb4[2] | ((uint)hb4[3] << 16);
      lw.x = (uint)lb4[0] | ((uint)lb4[1] << 16);
      lw.y = (uint)lb4[2] | ((uint)lb4[3] << 16);
      *(uint2*)&hHi[off] = hw;
      *(uint2*)&hLo[off] = lw;
    }
    __syncthreads();
  }

  short8 a1[2];
  #pragma unroll
  for (int f = 0; f < 2; ++f){
    const float* w = WO + WO_W1 + (q * 16 + nlo) * 64 + f * 32 + quad * 8;
    short8 a;
    #pragma unroll
    for (int j = 0; j < 8; ++j) a[j] = (short)f2bf(w[j]);
    a1[f] = a;
  }
  float4v b1v = *(const float4v*)(WO + WO_B1 + q * 16 + quad * 4);
  #pragma unroll
  for (int nt = 0; nt < 2; ++nt){
    const int hb = (nt * 16 + nlo) * 72 + quad * 8;
    float4v a = b1v;
    a = MFMA16(a1[0], *(const short8*)&hHi[hb], a);
    a = MFMA16(a1[1], *(const short8*)&hHi[hb + 32], a);
    a = MFMA16(a1[0], *(const short8*)&hLo[hb], a);
    a = MFMA16(a1[1], *(const short8*)&hLo[hb + 32], a);
    float4v rv;
    #pragma unroll
    for (int r = 0; r < 4; ++r) rv[r] = fmaxf(a[r], 0.0f);
    *(float4v*)&x1T[(nt * 16 + nlo) * 68 + q * 16 + quad * 4] = rv;
  }
  __syncthreads();

  const int bloc = threadIdx.x >> 3;       // 0..31
  const int r0 = threadIdx.x & 7;
  const float* w2 = WO + WO_W2;
  const float* b2 = WO + WO_B2;
  for (int r = r0; r < 9; r += 8){
    float acc = b2[r];
    const float* wr = w2 + r * 64;
    #pragma unroll
    for (int k = 0; k < 64; ++k) acc = fmaf(wr[k], x1T[bloc * 68 + k], acc);
    if (isbf) ((u16*)out)[(size_t)(b0 + bloc) * 9 + r] = f2bf(acc);
    else      ((float*)out)[(size_t)(b0 + bloc) * 9 + r] = acc;
  }
}

extern "C" void kernel_launch(void* const* d_in, const int* in_sizes, int n_in,
                              void* d_out, int out_size, void* d_ws, size_t ws_size,
                              hipStream_t stream){
  char* ws = (char*)d_ws;
  float* WF = (float*)ws;
  size_t off = ((size_t)WF_TOTAL * 4 + 255) & ~(size_t)255;
  u16* sTx = (u16*)(ws + off);    off += (size_t)3 * NB * 512 * 2;
  u16* xpartT = (u16*)(ws + off); off += (size_t)3 * NB * 128 * 2;
  int* nar = (int*)(ws + off);    off += (size_t)3 * NB * 4;
  int* flag = (int*)(ws + off);   off += 256;
  int* cnt  = (int*)(ws + off);   off += 256;
  int* ghist = (int*)(ws + off);  off += 3 * 65 * 4 + 64;
  int* idx  = (int*)(ws + off);   off += (size_t)3 * NB * 4;
  int* krank = (int*)(ws + off);  off += (size_t)3 * NB * 4;
  u16* zxp  = (u16*)(ws + off);   off += 2 * 128 * 2;

  PtrTab P;
  for (int i = 0; i < 36; ++i) P.p[i] = d_in[i];

  SegTab S;
  int si = 0;
  for (int t = 0; t < 3; ++t){
    int base = 4 + 8 * t;
    int d = t * TW;
    S.s[si++] = { base + 2, -1,       0,     d + W_WIH,         1536 };
    S.s[si++] = { base + 3, -1,       0,     d + W_WHH,         8192 };
    S.s[si++] = { base + 3, -1,       8192,  d + W_WHH + 8192,  8192 };
    S.s[si++] = { base + 4, base + 5, 0,     d + W_BSUM,        256  };
    S.s[si++] = { base + 6, -1,       0,     d + W_WTS,         4096 };
    S.s[si++] = { base + 7, -1,       0,     d + W_BTS,         64   };
    S.s[si++] = { base + 0, -1,       0,     d + W_WOS,         448  };
    S.s[si++] = { base + 1, -1,       0,     d + W_BOS,         64   };
  }
  {
    int O = W_OUT;
    for (int k = 0; k < 4; ++k)
      S.s[si++] = { 28, -1, k * 8192, O + WO_WIHO + k * 8192, 8192 };
    S.s[si++] = { 29, -1, 0,    O + WO_WHHO,        8192 };
    S.s[si++] = { 29, -1, 8192, O + WO_WHHO + 8192, 8192 };
    S.s[si++] = { 30, 31, 0,    O + WO_BSUM,        256  };
    S.s[si++] = { 32, -1, 0,    O + WO_W1,          4096 };
    S.s[si++] = { 33, -1, 0,    O + WO_B1,          64   };
    S.s[si++] = { 34, -1, 0,    O + WO_W2,          576  };
    S.s[si++] = { 35, -1, 0,    O + WO_B2,          9    };
  }

  const int* hl_ptr = (const int*)d_in[3];

  kweights<<<dim3(35), 256, 0, stream>>>(P, S, WF, d_in[7], flag, ghist);
  kprep<<<dim3(NB / 4, 3), 256, 0, stream>>>(d_in[0], d_in[1], hl_ptr, WF, sTx, nar, xpartT, flag, ghist, krank);
  kscatW<<<dim3(16, 3), 256, 0, stream>>>(hl_ptr, nar, ghist, krank, idx, cnt);
  kmainM<<<dim3(513, 3), 256, 0, stream>>>(nar, WF, sTx, xpartT, idx, cnt, zxp);
  kfinalM<<<dim3(NB / 32), 256, 0, stream>>>(WF, xpartT, zxp, hl_ptr, d_out, flag);
}